// Round 4
// baseline (445.025 us; speedup 1.0000x reference)
//
#include <hip/hip_runtime.h>
#include <math.h>

#define NN 4096
#define DD 512
#define INV_TAU 5.0f
#define EPSV 1e-15f

typedef unsigned short u16;
typedef __attribute__((ext_vector_type(8))) short short8;
typedef __attribute__((ext_vector_type(4))) float f32x4;

__device__ __forceinline__ void gld16(const void* g, void* l) {
  __builtin_amdgcn_global_load_lds(
      (const __attribute__((address_space(1))) unsigned int*)g,
      (__attribute__((address_space(3))) unsigned int*)l, 16, 0, 0);
}

__device__ __forceinline__ float bf2f(u16 u) {
  return __uint_as_float(((unsigned)u) << 16);
}
__device__ __forceinline__ u16 f2bf(float x) {  // RNE
  unsigned u = __float_as_uint(x);
  u += 0x7fff + ((u >> 16) & 1);
  return (u16)(u >> 16);
}

__device__ __forceinline__ float wave_sum(float v) {
#pragma unroll
  for (int o = 32; o > 0; o >>= 1) v += __shfl_down(v, o, 64);
  return v;
}

// ---- prep: z1/z2 fp32 -> bf16 + column means; weights fp32 -> bf16 ----------
// grid (64, 3): y=0 z1, y=1 z2, y=2 weights (lw1|lw2 -> Wb contiguous)
__global__ __launch_bounds__(256) void prep(
    const float* __restrict__ z1, const float* __restrict__ z2,
    const float* __restrict__ lw1, const float* __restrict__ lw2,
    u16* __restrict__ Ab, u16* __restrict__ Wb, float* __restrict__ s1,
    float* __restrict__ s2) {
  const int tid = threadIdx.x;
  if (blockIdx.y == 2) {
#pragma unroll
    for (int k = 0; k < 8; ++k) {
      const int idx = blockIdx.x * 256 + tid + k * 16384;  // float4 index
      const float* s = (idx < 65536) ? &lw1[(size_t)idx * 4]
                                     : &lw2[(size_t)(idx - 65536) * 4];
      float4 v = *(const float4*)s;
      unsigned long long pk = (unsigned long long)f2bf(v.x) |
                              ((unsigned long long)f2bf(v.y) << 16) |
                              ((unsigned long long)f2bf(v.z) << 32) |
                              ((unsigned long long)f2bf(v.w) << 48);
      *(unsigned long long*)&Wb[(size_t)idx * 4] = pk;
    }
    return;
  }
  const float* z = blockIdx.y ? z2 : z1;
  u16* dst = Ab + (size_t)blockIdx.y * ((size_t)NN * DD);
  float* sdst = blockIdx.y ? s2 : s1;
  const int col4 = tid & 127;
  const int rg = tid >> 7;
  const int r0 = blockIdx.x * 64;
  float4 acc = make_float4(0.f, 0.f, 0.f, 0.f);
#pragma unroll 4
  for (int k = 0; k < 32; ++k) {
    const int r = r0 + rg + k * 2;
    float4 v = *(const float4*)&z[(size_t)r * DD + col4 * 4];
    acc.x += v.x; acc.y += v.y; acc.z += v.z; acc.w += v.w;
    unsigned long long pk = (unsigned long long)f2bf(v.x) |
                            ((unsigned long long)f2bf(v.y) << 16) |
                            ((unsigned long long)f2bf(v.z) << 32) |
                            ((unsigned long long)f2bf(v.w) << 48);
    *(unsigned long long*)&dst[(size_t)r * DD + col4 * 4] = pk;
  }
  const float inv = 1.f / NN;
  atomicAdd(&sdst[col4 * 4 + 0], acc.x * inv);
  atomicAdd(&sdst[col4 * 4 + 1], acc.y * inv);
  atomicAdd(&sdst[col4 * 4 + 2], acc.z * inv);
  atomicAdd(&sdst[col4 * 4 + 3], acc.w * inv);
}

// ------------- MFMA NT GEMM, pipelined: out = act(A@Bw^T + bias) -------------
// A:[2,4096,512] bf16 (batch via z), Bw:[512,512] bf16. tile 128x64, 4 waves.
template <int ACT>
__global__ __launch_bounds__(256) void gemm_mfma(
    const u16* __restrict__ A, const u16* __restrict__ Bw,
    const float* __restrict__ bias, const float* __restrict__ alpha_p,
    u16* __restrict__ out) {
  __shared__ __align__(16) u16 sA[2][128 * 32], sB[2][64 * 32];
  const int tid = threadIdx.x, w = tid >> 6, lane = tid & 63;
  const int rq = lane >> 2, cq = (lane & 3) * 8;
  const int quad = lane >> 4, m16 = lane & 15;
  const int wi = w >> 1, wj = w & 1;
  const int i0 = blockIdx.y * 128, j0 = blockIdx.x * 64;
  const u16* Apan = A + (size_t)blockIdx.z * ((size_t)NN * DD);
  u16* ob = out + (size_t)blockIdx.z * ((size_t)NN * DD);
  // staging: w0 A rows 0-63, w1 A rows 64-127, w2 B rows 0-63, w3 idle
  const bool st = (w < 3);
  const u16* gs = (w == 2) ? Bw : Apan;
  const int gr0 = (w == 2) ? (j0 + rq) : (i0 + (w == 1 ? 64 : 0) + rq);
  u16* lb0 = (w == 2) ? sB[0] : &sA[0][(w == 1 ? 64 : 0) * 32];
  u16* lb1 = (w == 2) ? sB[1] : &sA[1][(w == 1 ? 64 : 0) * 32];
  if (st) {
#pragma unroll
    for (int rr = 0; rr < 64; rr += 16)
      gld16(&gs[(size_t)(gr0 + rr) * DD + cq], lb0 + rr * 32);
  }
  f32x4 acc[4][2] = {};
  for (int kc = 0; kc < 16; ++kc) {
    __syncthreads();
    if (kc < 15 && st) {
      const int kn = (kc + 1) * 32;
      u16* d = (kc & 1) ? lb0 : lb1;
#pragma unroll
      for (int rr = 0; rr < 64; rr += 16)
        gld16(&gs[(size_t)(gr0 + rr) * DD + kn + cq], d + rr * 32);
    }
    const u16* As = sA[kc & 1];
    const u16* Bs = sB[kc & 1];
    short8 bj[2];
#pragma unroll
    for (int sj = 0; sj < 2; ++sj)
      bj[sj] = *(const short8*)&Bs[(wj * 32 + sj * 16 + m16) * 32 + quad * 8];
#pragma unroll
    for (int si = 0; si < 4; ++si) {
      short8 ai = *(const short8*)&As[(wi * 64 + si * 16 + m16) * 32 + quad * 8];
#pragma unroll
      for (int sj = 0; sj < 2; ++sj)
        acc[si][sj] = __builtin_amdgcn_mfma_f32_16x16x32_bf16(
            ai, bj[sj], acc[si][sj], 0, 0, 0);
    }
  }
  const float al = ACT ? alpha_p[0] : 0.f;
#pragma unroll
  for (int si = 0; si < 4; ++si)
#pragma unroll
    for (int sj = 0; sj < 2; ++sj) {
      const int col = j0 + wj * 32 + sj * 16 + m16;
      const float bv = bias[col];
#pragma unroll
      for (int r = 0; r < 4; ++r) {
        const int row = i0 + wi * 64 + si * 16 + quad * 4 + r;
        float x = acc[si][sj][r] + bv;
        if (ACT) x = (x >= 0.f) ? x : al * x;
        ob[(size_t)row * DD + col] = f2bf(x);
      }
    }
}

// ---------------- row inverse L2 norm: bf16 h -> fp32 invn -------------------
__global__ __launch_bounds__(256) void rowinvnorm(const u16* __restrict__ h,
                                                  float* __restrict__ invn) {
  const int row = blockIdx.x * 4 + (threadIdx.x >> 6);
  const int lane = threadIdx.x & 63;
  short8 v = *(const short8*)&h[(size_t)row * DD + lane * 8];
  float s = 0.f;
#pragma unroll
  for (int k = 0; k < 8; ++k) {
    const float f = bf2f(((const u16*)&v)[k]);
    s += f * f;
  }
  s = wave_sum(s);
  if (lane == 0) invn[row] = 1.f / fmaxf(sqrtf(s), 1e-12f);
}

// ------------- fused similarity (MFMA): 3 products + inv-scale + exp + sums --
// tile 128x128, 256 thr (4 waves), per-wave 64x64 register tile.
// zb: [r11s, r11m, r12s, r12m, c12s, c12m, c22s, c22m] x NN.
__global__ __launch_bounds__(256, 2) void sim_mfma(
    const u16* __restrict__ na, const u16* __restrict__ nb,
    const float* __restrict__ invA, const float* __restrict__ invB,
    const int* __restrict__ mask, float* __restrict__ zb) {
  __shared__ __align__(16) u16 sP[2][4][128 * 32];  // 64 KiB
  const int tid = threadIdx.x, w = tid >> 6, lane = tid & 63;
  const int rq = lane >> 2, cq = (lane & 3) * 8;
  const int quad = lane >> 4, m16 = lane & 15;
  const int wi = w >> 1, wj = w & 1;
  const int i0 = blockIdx.y * 128, j0 = blockIdx.x * 128;
  // staging: wave w stages panel w: 0 na_i, 1 nb_i, 2 na_j, 3 nb_j
  const u16* gs = (w & 1) ? nb : na;
  const int gr0 = ((w < 2) ? i0 : j0) + rq;
  u16* lb0 = &sP[0][w][0];
  u16* lb1 = &sP[1][w][0];
#pragma unroll
  for (int rr = 0; rr < 128; rr += 16)
    gld16(&gs[(size_t)(gr0 + rr) * DD + cq], lb0 + rr * 32);
  f32x4 a11[4][4] = {}, a12[4][4] = {}, a22[4][4] = {};
  for (int kc = 0; kc < 16; ++kc) {
    __syncthreads();
    if (kc < 15) {
      const int kn = (kc + 1) * 32;
      u16* d = (kc & 1) ? lb0 : lb1;
#pragma unroll
      for (int rr = 0; rr < 128; rr += 16)
        gld16(&gs[(size_t)(gr0 + rr) * DD + kn + cq], d + rr * 32);
    }
    const u16* Ai = sP[kc & 1][0];
    const u16* Bi = sP[kc & 1][1];
    const u16* Aj = sP[kc & 1][2];
    const u16* Bj = sP[kc & 1][3];
    short8 aj[4], bj[4];
#pragma unroll
    for (int sj = 0; sj < 4; ++sj) {
      aj[sj] = *(const short8*)&Aj[(wj * 64 + sj * 16 + m16) * 32 + quad * 8];
      bj[sj] = *(const short8*)&Bj[(wj * 64 + sj * 16 + m16) * 32 + quad * 8];
    }
#pragma unroll
    for (int si = 0; si < 4; ++si) {
      short8 ai = *(const short8*)&Ai[(wi * 64 + si * 16 + m16) * 32 + quad * 8];
      short8 bi = *(const short8*)&Bi[(wi * 64 + si * 16 + m16) * 32 + quad * 8];
#pragma unroll
      for (int sj = 0; sj < 4; ++sj) {
        a11[si][sj] = __builtin_amdgcn_mfma_f32_16x16x32_bf16(ai, aj[sj], a11[si][sj], 0, 0, 0);
        a12[si][sj] = __builtin_amdgcn_mfma_f32_16x16x32_bf16(ai, bj[sj], a12[si][sj], 0, 0, 0);
        a22[si][sj] = __builtin_amdgcn_mfma_f32_16x16x32_bf16(bi, bj[sj], a22[si][sj], 0, 0, 0);
      }
    }
  }
  __syncthreads();
  float* rred = (float*)&sP[0][0][0];  // [4][128]
  float* cred = rred + 512;            // [4][128]
  rred[tid] = 0.f; rred[tid + 256] = 0.f;
  rred[tid + 512] = 0.f; rred[tid + 768] = 0.f;
  __syncthreads();
  float4 iAr[4], iBr[4];
  float iAc[4], iBc[4];
#pragma unroll
  for (int s = 0; s < 4; ++s) {
    iAr[s] = *(const float4*)&invA[i0 + wi * 64 + s * 16 + quad * 4];
    iBr[s] = *(const float4*)&invB[i0 + wi * 64 + s * 16 + quad * 4];
    iAc[s] = invA[j0 + wj * 64 + s * 16 + m16];
    iBc[s] = invB[j0 + wj * 64 + s * 16 + m16];
  }
  float cs12[4] = {}, cm12[4] = {}, cs22[4] = {}, cm22[4] = {};
#pragma unroll
  for (int si = 0; si < 4; ++si) {
    float rs11[4] = {}, rm11[4] = {}, rs12[4] = {}, rm12[4] = {};
    const float ia4[4] = {iAr[si].x, iAr[si].y, iAr[si].z, iAr[si].w};
    const float ib4[4] = {iBr[si].x, iBr[si].y, iBr[si].z, iBr[si].w};
#pragma unroll
    for (int sj = 0; sj < 4; ++sj) {
      const int gj = j0 + wj * 64 + sj * 16 + m16;
#pragma unroll
      for (int r = 0; r < 4; ++r) {
        const int gi = i0 + wi * 64 + si * 16 + quad * 4 + r;
        const float mv = (float)mask[(size_t)gi * NN + gj];
        const float e11 = __expf(a11[si][sj][r] * ia4[r] * iAc[sj] * INV_TAU);
        const float e12 = __expf(a12[si][sj][r] * ia4[r] * iBc[sj] * INV_TAU);
        const float e22 = __expf(a22[si][sj][r] * ib4[r] * iBc[sj] * INV_TAU);
        rs11[r] += e11; rm11[r] += e11 * mv;
        rs12[r] += e12; rm12[r] += e12 * mv;
        cs12[sj] += e12; cm12[sj] += e12 * mv;
        cs22[sj] += e22; cm22[sj] += e22 * mv;
      }
    }
#pragma unroll
    for (int r = 0; r < 4; ++r) {
      float v0 = rs11[r], v1 = rm11[r], v2 = rs12[r], v3 = rm12[r];
#pragma unroll
      for (int o = 1; o < 16; o <<= 1) {
        v0 += __shfl_xor(v0, o, 64);
        v1 += __shfl_xor(v1, o, 64);
        v2 += __shfl_xor(v2, o, 64);
        v3 += __shfl_xor(v3, o, 64);
      }
      if (m16 == 0) {
        const int il = wi * 64 + si * 16 + quad * 4 + r;
        atomicAdd(&rred[0 * 128 + il], v0);
        atomicAdd(&rred[1 * 128 + il], v1);
        atomicAdd(&rred[2 * 128 + il], v2);
        atomicAdd(&rred[3 * 128 + il], v3);
      }
    }
  }
#pragma unroll
  for (int sj = 0; sj < 4; ++sj) {
    float v0 = cs12[sj], v1 = cm12[sj], v2 = cs22[sj], v3 = cm22[sj];
    v0 += __shfl_xor(v0, 16, 64); v0 += __shfl_xor(v0, 32, 64);
    v1 += __shfl_xor(v1, 16, 64); v1 += __shfl_xor(v1, 32, 64);
    v2 += __shfl_xor(v2, 16, 64); v2 += __shfl_xor(v2, 32, 64);
    v3 += __shfl_xor(v3, 16, 64); v3 += __shfl_xor(v3, 32, 64);
    if (lane < 16) {
      const int jl = wj * 64 + sj * 16 + lane;
      atomicAdd(&cred[0 * 128 + jl], v0);
      atomicAdd(&cred[1 * 128 + jl], v1);
      atomicAdd(&cred[2 * 128 + jl], v2);
      atomicAdd(&cred[3 * 128 + jl], v3);
    }
  }
  __syncthreads();
  if (tid < 128) {
#pragma unroll
    for (int q = 0; q < 4; ++q)
      atomicAdd(&zb[q * NN + i0 + tid], rred[q * 128 + tid]);
  } else {
    const int jl = tid - 128;
#pragma unroll
    for (int q = 0; q < 4; ++q)
      atomicAdd(&zb[(4 + q) * NN + j0 + jl], cred[q * 128 + jl]);
  }
}

// ---------------- local InfoNCE finalize -------------------------------------
__global__ __launch_bounds__(256) void local_fin(const float* __restrict__ zb,
                                                 float* __restrict__ scal) {
  const int i = blockIdx.x * 256 + threadIdx.x;
  const float r11 = zb[i], r11m = zb[NN + i];
  const float r12 = zb[2 * NN + i], r12m = zb[3 * NN + i];
  const float c12 = zb[4 * NN + i], c12m = zb[5 * NN + i];
  const float c22 = zb[6 * NN + i], c22m = zb[7 * NN + i];
  float l1 = -logf(r12m / (r11 + r12 - r11m));
  float l2 = -logf(c12m / (c22 + c12 - c22m));
  l1 = wave_sum(l1);
  l2 = wave_sum(l2);
  __shared__ float b1[4], b2[4];
  const int lane = threadIdx.x & 63, wid = threadIdx.x >> 6;
  if (lane == 0) { b1[wid] = l1; b2[wid] = l2; }
  __syncthreads();
  if (threadIdx.x == 0) {
    atomicAdd(&scal[0], b1[0] + b1[1] + b1[2] + b1[3]);
    atomicAdd(&scal[1], b2[0] + b2[1] + b2[2] + b2[3]);
  }
}

// ---------------- fused global projector chain (2 blocks) --------------------
__global__ __launch_bounds__(256) void globchain(
    const float* __restrict__ gw1, const float* __restrict__ gb1,
    const float* __restrict__ ga, const float* __restrict__ gw2,
    const float* __restrict__ gb2, const float* __restrict__ Wd,
    const float* __restrict__ s1, const float* __restrict__ s2,
    float* __restrict__ summ1, float* __restrict__ summ2) {
  __shared__ float xv[512], tv[512];
  const int ch = blockIdx.x;
  const float* s = ch ? s2 : s1;
  float* outp = ch ? summ2 : summ1;
  const int tid = threadIdx.x;
  const int r1 = tid, r2 = tid + 256;
  xv[r1] = s[r1];
  xv[r2] = s[r2];
  __syncthreads();
  const float al = ga[0];
  float d0 = 0.f, d1 = 0.f;
  for (int k = 0; k < 512; k += 4) {
    float4 a = *(const float4*)&gw1[(size_t)r1 * 512 + k];
    float4 b = *(const float4*)&gw1[(size_t)r2 * 512 + k];
    d0 += a.x * xv[k] + a.y * xv[k + 1] + a.z * xv[k + 2] + a.w * xv[k + 3];
    d1 += b.x * xv[k] + b.y * xv[k + 1] + b.z * xv[k + 2] + b.w * xv[k + 3];
  }
  d0 += gb1[r1]; d1 += gb1[r2];
  tv[r1] = (d0 >= 0.f) ? d0 : al * d0;
  tv[r2] = (d1 >= 0.f) ? d1 : al * d1;
  __syncthreads();
  d0 = 0.f; d1 = 0.f;
  for (int k = 0; k < 512; k += 4) {
    float4 a = *(const float4*)&gw2[(size_t)r1 * 512 + k];
    float4 b = *(const float4*)&gw2[(size_t)r2 * 512 + k];
    d0 += a.x * tv[k] + a.y * tv[k + 1] + a.z * tv[k + 2] + a.w * tv[k + 3];
    d1 += b.x * tv[k] + b.y * tv[k + 1] + b.z * tv[k + 2] + b.w * tv[k + 3];
  }
  __syncthreads();
  xv[r1] = d0 + gb2[r1];
  xv[r2] = d1 + gb2[r2];
  __syncthreads();
  d0 = 0.f; d1 = 0.f;
  for (int k = 0; k < 512; k += 4) {
    float4 a = *(const float4*)&Wd[(size_t)r1 * 512 + k];
    float4 b = *(const float4*)&Wd[(size_t)r2 * 512 + k];
    d0 += a.x * xv[k] + a.y * xv[k + 1] + a.z * xv[k + 2] + a.w * xv[k + 3];
    d1 += b.x * xv[k] + b.y * xv[k + 1] + b.z * xv[k + 2] + b.w * xv[k + 3];
  }
  outp[r1] = d0;
  outp[r2] = d1;
}

// ---------------- paired sigmoid/log reduce (bf16 z) -------------------------
__global__ __launch_bounds__(256) void logsig2(
    const u16* __restrict__ zb16, const float* __restrict__ sm1,
    const float* __restrict__ sm2, float* __restrict__ scal) {
  const int ch = blockIdx.y;
  const u16* z = zb16 + (size_t)ch * ((size_t)NN * DD);
  const float* sp = ch ? sm2 : sm1;
  const float* sn = ch ? sm1 : sm2;
  const int lane = threadIdx.x & 63, wv = threadIdx.x >> 6;
  float sp8[8], sn8[8];
#pragma unroll
  for (int k = 0; k < 8; ++k) {
    sp8[k] = sp[lane * 8 + k];
    sn8[k] = sn[lane * 8 + k];
  }
  float accP = 0.f, accN = 0.f;
#pragma unroll
  for (int rr = 0; rr < 4; ++rr) {
    const int row = blockIdx.x * 16 + wv * 4 + rr;
    short8 v = *(const short8*)&z[(size_t)row * DD + lane * 8];
    float dp = 0.f, dn = 0.f;
#pragma unroll
    for (int k = 0; k < 8; ++k) {
      const float f = bf2f(((const u16*)&v)[k]);
      dp = fmaf(f, sp8[k], dp);
      dn = fmaf(f, sn8[k], dn);
    }
    dp = wave_sum(dp);
    dn = wave_sum(dn);
    if (lane == 0) {
      accP += -logf(1.f / (1.f + __expf(-dp)) + EPSV);
      accN += -logf(1.f - 1.f / (1.f + __expf(-dn)) + EPSV);
    }
  }
  if (lane == 0) {
    atomicAdd(&scal[ch ? 4 : 2], accP);
    atomicAdd(&scal[ch ? 3 : 5], accN);
  }
}

// ---------------- final combine ----------------------------------------------
__global__ void combine(const float* __restrict__ scal, float* __restrict__ out) {
  const float local = 0.5f * (scal[0] + scal[1]) * (1.f / NN);
  const float glob = 0.25f * (scal[2] + scal[3] + scal[4] + scal[5]) * (1.f / NN);
  out[0] = 0.5f * local + 0.5f * glob;
}

extern "C" void kernel_launch(void* const* d_in, const int* in_sizes, int n_in,
                              void* d_out, int out_size, void* d_ws,
                              size_t ws_size, hipStream_t stream) {
  const float* z1 = (const float*)d_in[0];
  const float* z2 = (const float*)d_in[1];
  const float* lw1 = (const float*)d_in[2];
  const float* lb1 = (const float*)d_in[3];
  const float* la = (const float*)d_in[4];
  const float* lw2 = (const float*)d_in[5];
  const float* lb2 = (const float*)d_in[6];
  const float* gw1 = (const float*)d_in[7];
  const float* gb1 = (const float*)d_in[8];
  const float* ga = (const float*)d_in[9];
  const float* gw2 = (const float*)d_in[10];
  const float* gb2 = (const float*)d_in[11];
  const float* W = (const float*)d_in[12];
  const int* mask = (const int*)d_in[13];
  float* out = (float*)d_out;

  const size_t ND = (size_t)NN * DD;
  u16* W1b = (u16*)d_ws;                  // [2][512*512] bf16 contiguous
  u16* W2b = W1b + 512 * 512;
  u16* Ab = W1b + 2 * 512 * 512;          // [2][N*D] bf16 (z)
  u16* Pb = Ab + 2 * ND;                  // [2][N*D] bf16 (prelu out)
  u16* Hb = Pb + 2 * ND;                  // [2][N*D] bf16 (projector out)
  float* invn = (float*)(Hb + 2 * ND);    // [2*NN]
  float* zbf = invn + 2 * NN;             // 8*NN (zeroed)
  float* s1 = zbf + 8 * NN;               // zeroed
  float* s2 = s1 + DD;                    // zeroed
  float* scal = s2 + DD;                  // [sum1,sum2,P1,Ng1,P2,Ng2] zeroed
  float* summ1 = scal + 16;
  float* summ2 = summ1 + DD;

  hipMemsetAsync(zbf, 0, (8 * NN + 2 * DD + 16) * sizeof(float), stream);

  dim3 blk(256);
  prep<<<dim3(64, 3), blk, 0, stream>>>(z1, z2, lw1, lw2, Ab, W1b, s1, s2);

  dim3 gg(8, 32, 2);  // 512/64, 4096/128, batch
  gemm_mfma<1><<<gg, blk, 0, stream>>>(Ab, W1b, lb1, la, Pb);
  gemm_mfma<0><<<gg, blk, 0, stream>>>(Pb, W2b, lb2, la, Hb);
  rowinvnorm<<<2 * NN / 4, blk, 0, stream>>>(Hb, invn);

  sim_mfma<<<dim3(NN / 128, NN / 128), blk, 0, stream>>>(
      Hb, Hb + ND, invn, invn + NN, mask, zbf);
  local_fin<<<NN / 256, blk, 0, stream>>>(zbf, scal);

  globchain<<<2, blk, 0, stream>>>(gw1, gb1, ga, gw2, gb2, W, s1, s2, summ1,
                                   summ2);
  logsig2<<<dim3(NN / 16, 2), blk, 0, stream>>>(Ab, summ1, summ2, scal);

  combine<<<1, 1, 0, stream>>>(scal, out);
}

// Round 5
// 339.427 us; speedup vs baseline: 1.3111x; 1.3111x over previous
//
#include <hip/hip_runtime.h>
#include <math.h>

#define NN 4096
#define DD 512
#define INV_TAU 5.0f
#define EPSV 1e-15f

typedef unsigned short u16;
typedef __attribute__((ext_vector_type(8))) short short8;
typedef __attribute__((ext_vector_type(4))) float f32x4;

__device__ __forceinline__ void gld16(const void* g, void* l) {
  __builtin_amdgcn_global_load_lds(
      (const __attribute__((address_space(1))) unsigned int*)g,
      (__attribute__((address_space(3))) unsigned int*)l, 16, 0, 0);
}

__device__ __forceinline__ float bf2f(u16 u) {
  return __uint_as_float(((unsigned)u) << 16);
}
__device__ __forceinline__ u16 f2bf(float x) {  // RNE
  unsigned u = __float_as_uint(x);
  u += 0x7fff + ((u >> 16) & 1);
  return (u16)(u >> 16);
}

__device__ __forceinline__ float wave_sum(float v) {
#pragma unroll
  for (int o = 32; o > 0; o >>= 1) v += __shfl_down(v, o, 64);
  return v;
}

__device__ __forceinline__ float invnorm(float n) {
  return 1.f / fmaxf(sqrtf(n), 1e-12f);
}

// ---- prep: z1/z2 fp32 -> bf16 + column means; weights fp32 -> bf16 ----------
// grid (64, 3): y=0 z1, y=1 z2, y=2 weights (lw1|lw2 -> Wb contiguous)
__global__ __launch_bounds__(256) void prep(
    const float* __restrict__ z1, const float* __restrict__ z2,
    const float* __restrict__ lw1, const float* __restrict__ lw2,
    u16* __restrict__ Ab, u16* __restrict__ Wb, float* __restrict__ s1,
    float* __restrict__ s2) {
  const int tid = threadIdx.x;
  if (blockIdx.y == 2) {
#pragma unroll
    for (int k = 0; k < 8; ++k) {
      const int idx = blockIdx.x * 256 + tid + k * 16384;  // float4 index
      const float* s = (idx < 65536) ? &lw1[(size_t)idx * 4]
                                     : &lw2[(size_t)(idx - 65536) * 4];
      float4 v = *(const float4*)s;
      unsigned long long pk = (unsigned long long)f2bf(v.x) |
                              ((unsigned long long)f2bf(v.y) << 16) |
                              ((unsigned long long)f2bf(v.z) << 32) |
                              ((unsigned long long)f2bf(v.w) << 48);
      *(unsigned long long*)&Wb[(size_t)idx * 4] = pk;
    }
    return;
  }
  const float* z = blockIdx.y ? z2 : z1;
  u16* dst = Ab + (size_t)blockIdx.y * ((size_t)NN * DD);
  float* sdst = blockIdx.y ? s2 : s1;
  const int col4 = tid & 127;
  const int rg = tid >> 7;
  const int r0 = blockIdx.x * 64;
  float4 acc = make_float4(0.f, 0.f, 0.f, 0.f);
#pragma unroll 4
  for (int k = 0; k < 32; ++k) {
    const int r = r0 + rg + k * 2;
    float4 v = *(const float4*)&z[(size_t)r * DD + col4 * 4];
    acc.x += v.x; acc.y += v.y; acc.z += v.z; acc.w += v.w;
    unsigned long long pk = (unsigned long long)f2bf(v.x) |
                            ((unsigned long long)f2bf(v.y) << 16) |
                            ((unsigned long long)f2bf(v.z) << 32) |
                            ((unsigned long long)f2bf(v.w) << 48);
    *(unsigned long long*)&dst[(size_t)r * DD + col4 * 4] = pk;
  }
  const float inv = 1.f / NN;
  atomicAdd(&sdst[col4 * 4 + 0], acc.x * inv);
  atomicAdd(&sdst[col4 * 4 + 1], acc.y * inv);
  atomicAdd(&sdst[col4 * 4 + 2], acc.z * inv);
  atomicAdd(&sdst[col4 * 4 + 3], acc.w * inv);
}

// ------------- MFMA NT GEMM, pipelined: out = act(A@Bw^T + bias) -------------
// A:[2,4096,512] bf16 (batch via z), Bw:[512,512] bf16. tile 128x64, 4 waves.
// NRM: also accumulate per-row sum of squares of the output into norm2.
template <int ACT, int NRM>
__global__ __launch_bounds__(256) void gemm_mfma(
    const u16* __restrict__ A, const u16* __restrict__ Bw,
    const float* __restrict__ bias, const float* __restrict__ alpha_p,
    u16* __restrict__ out, float* __restrict__ norm2) {
  __shared__ __align__(16) u16 sA[2][128 * 32], sB[2][64 * 32];
  const int tid = threadIdx.x, w = tid >> 6, lane = tid & 63;
  const int rq = lane >> 2, cq = (lane & 3) * 8;
  const int quad = lane >> 4, m16 = lane & 15;
  const int wi = w >> 1, wj = w & 1;
  const int i0 = blockIdx.y * 128, j0 = blockIdx.x * 64;
  const u16* Apan = A + (size_t)blockIdx.z * ((size_t)NN * DD);
  u16* ob = out + (size_t)blockIdx.z * ((size_t)NN * DD);
  float* npan = norm2 + (size_t)blockIdx.z * NN;
  // staging: w0 A rows 0-63, w1 A rows 64-127, w2 B rows 0-63, w3 idle
  const bool st = (w < 3);
  const u16* gs = (w == 2) ? Bw : Apan;
  const int gr0 = (w == 2) ? (j0 + rq) : (i0 + (w == 1 ? 64 : 0) + rq);
  u16* lb0 = (w == 2) ? sB[0] : &sA[0][(w == 1 ? 64 : 0) * 32];
  u16* lb1 = (w == 2) ? sB[1] : &sA[1][(w == 1 ? 64 : 0) * 32];
  if (st) {
#pragma unroll
    for (int rr = 0; rr < 64; rr += 16)
      gld16(&gs[(size_t)(gr0 + rr) * DD + cq], lb0 + rr * 32);
  }
  f32x4 acc[4][2] = {};
  for (int kc = 0; kc < 16; ++kc) {
    __syncthreads();
    if (kc < 15 && st) {
      const int kn = (kc + 1) * 32;
      u16* d = (kc & 1) ? lb0 : lb1;
#pragma unroll
      for (int rr = 0; rr < 64; rr += 16)
        gld16(&gs[(size_t)(gr0 + rr) * DD + kn + cq], d + rr * 32);
    }
    const u16* As = sA[kc & 1];
    const u16* Bs = sB[kc & 1];
    short8 bj[2];
#pragma unroll
    for (int sj = 0; sj < 2; ++sj)
      bj[sj] = *(const short8*)&Bs[(wj * 32 + sj * 16 + m16) * 32 + quad * 8];
#pragma unroll
    for (int si = 0; si < 4; ++si) {
      short8 ai = *(const short8*)&As[(wi * 64 + si * 16 + m16) * 32 + quad * 8];
#pragma unroll
      for (int sj = 0; sj < 2; ++sj)
        acc[si][sj] = __builtin_amdgcn_mfma_f32_16x16x32_bf16(
            ai, bj[sj], acc[si][sj], 0, 0, 0);
    }
  }
  const float al = ACT ? alpha_p[0] : 0.f;
  float ssq[4][4] = {};
#pragma unroll
  for (int si = 0; si < 4; ++si)
#pragma unroll
    for (int sj = 0; sj < 2; ++sj) {
      const int col = j0 + wj * 32 + sj * 16 + m16;
      const float bv = bias[col];
#pragma unroll
      for (int r = 0; r < 4; ++r) {
        const int row = i0 + wi * 64 + si * 16 + quad * 4 + r;
        float x = acc[si][sj][r] + bv;
        if (ACT) x = (x >= 0.f) ? x : al * x;
        const u16 xb = f2bf(x);
        ob[(size_t)row * DD + col] = xb;
        if (NRM) {
          const float xf = bf2f(xb);  // norm of the rounded values (matches sim)
          ssq[si][r] += xf * xf;
        }
      }
    }
  if (NRM) {
#pragma unroll
    for (int si = 0; si < 4; ++si)
#pragma unroll
      for (int r = 0; r < 4; ++r) {
        float s = ssq[si][r];
        s += __shfl_xor(s, 1, 64);
        s += __shfl_xor(s, 2, 64);
        s += __shfl_xor(s, 4, 64);
        s += __shfl_xor(s, 8, 64);
        if (m16 == 0)
          atomicAdd(&npan[i0 + wi * 64 + si * 16 + quad * 4 + r], s);
      }
  }
}

// ------------- fused similarity (MFMA): 3 products + inv-scale + exp + sums --
// tile 128x128, 256 thr (4 waves), per-wave 64x64 register tile.
// zb: [r11s, r11m, r12s, r12m, c12s, c12m, c22s, c22m] x NN.
__global__ __launch_bounds__(256, 2) void sim_mfma(
    const u16* __restrict__ na, const u16* __restrict__ nb,
    const float* __restrict__ n2A, const float* __restrict__ n2B,
    const int* __restrict__ mask, float* __restrict__ zb) {
  __shared__ __align__(16) u16 sP[2][4][128 * 32];  // 64 KiB
  const int tid = threadIdx.x, w = tid >> 6, lane = tid & 63;
  const int rq = lane >> 2, cq = (lane & 3) * 8;
  const int quad = lane >> 4, m16 = lane & 15;
  const int wi = w >> 1, wj = w & 1;
  const int i0 = blockIdx.y * 128, j0 = blockIdx.x * 128;
  // staging: wave w stages panel w: 0 na_i, 1 nb_i, 2 na_j, 3 nb_j
  const u16* gs = (w & 1) ? nb : na;
  const int gr0 = ((w < 2) ? i0 : j0) + rq;
  u16* lb0 = &sP[0][w][0];
  u16* lb1 = &sP[1][w][0];
#pragma unroll
  for (int rr = 0; rr < 128; rr += 16)
    gld16(&gs[(size_t)(gr0 + rr) * DD + cq], lb0 + rr * 32);
  f32x4 a11[4][4] = {}, a12[4][4] = {}, a22[4][4] = {};
  for (int kc = 0; kc < 16; ++kc) {
    __syncthreads();
    if (kc < 15) {
      const int kn = (kc + 1) * 32;
      u16* d = (kc & 1) ? lb0 : lb1;
#pragma unroll
      for (int rr = 0; rr < 128; rr += 16)
        gld16(&gs[(size_t)(gr0 + rr) * DD + kn + cq], d + rr * 32);
    }
    const u16* Ai = sP[kc & 1][0];
    const u16* Bi = sP[kc & 1][1];
    const u16* Aj = sP[kc & 1][2];
    const u16* Bj = sP[kc & 1][3];
    short8 aj[4], bj[4];
#pragma unroll
    for (int sj = 0; sj < 4; ++sj) {
      aj[sj] = *(const short8*)&Aj[(wj * 64 + sj * 16 + m16) * 32 + quad * 8];
      bj[sj] = *(const short8*)&Bj[(wj * 64 + sj * 16 + m16) * 32 + quad * 8];
    }
#pragma unroll
    for (int si = 0; si < 4; ++si) {
      short8 ai = *(const short8*)&Ai[(wi * 64 + si * 16 + m16) * 32 + quad * 8];
      short8 bi = *(const short8*)&Bi[(wi * 64 + si * 16 + m16) * 32 + quad * 8];
#pragma unroll
      for (int sj = 0; sj < 4; ++sj) {
        a11[si][sj] = __builtin_amdgcn_mfma_f32_16x16x32_bf16(ai, aj[sj], a11[si][sj], 0, 0, 0);
        a12[si][sj] = __builtin_amdgcn_mfma_f32_16x16x32_bf16(ai, bj[sj], a12[si][sj], 0, 0, 0);
        a22[si][sj] = __builtin_amdgcn_mfma_f32_16x16x32_bf16(bi, bj[sj], a22[si][sj], 0, 0, 0);
      }
    }
  }
  __syncthreads();
  float* rred = (float*)&sP[0][0][0];  // [4][128]
  float* cred = rred + 512;            // [4][128]
  rred[tid] = 0.f; rred[tid + 256] = 0.f;
  rred[tid + 512] = 0.f; rred[tid + 768] = 0.f;
  __syncthreads();
  float4 iAr[4], iBr[4];
  float iAc[4], iBc[4];
#pragma unroll
  for (int s = 0; s < 4; ++s) {
    float4 a = *(const float4*)&n2A[i0 + wi * 64 + s * 16 + quad * 4];
    float4 b = *(const float4*)&n2B[i0 + wi * 64 + s * 16 + quad * 4];
    iAr[s] = make_float4(invnorm(a.x), invnorm(a.y), invnorm(a.z), invnorm(a.w));
    iBr[s] = make_float4(invnorm(b.x), invnorm(b.y), invnorm(b.z), invnorm(b.w));
    iAc[s] = invnorm(n2A[j0 + wj * 64 + s * 16 + m16]);
    iBc[s] = invnorm(n2B[j0 + wj * 64 + s * 16 + m16]);
  }
  float cs12[4] = {}, cm12[4] = {}, cs22[4] = {}, cm22[4] = {};
#pragma unroll
  for (int si = 0; si < 4; ++si) {
    float rs11[4] = {}, rm11[4] = {}, rs12[4] = {}, rm12[4] = {};
    const float ia4[4] = {iAr[si].x, iAr[si].y, iAr[si].z, iAr[si].w};
    const float ib4[4] = {iBr[si].x, iBr[si].y, iBr[si].z, iBr[si].w};
#pragma unroll
    for (int sj = 0; sj < 4; ++sj) {
      const int gj = j0 + wj * 64 + sj * 16 + m16;
#pragma unroll
      for (int r = 0; r < 4; ++r) {
        const int gi = i0 + wi * 64 + si * 16 + quad * 4 + r;
        const float mv = (float)mask[(size_t)gi * NN + gj];
        const float e11 = __expf(a11[si][sj][r] * ia4[r] * iAc[sj] * INV_TAU);
        const float e12 = __expf(a12[si][sj][r] * ia4[r] * iBc[sj] * INV_TAU);
        const float e22 = __expf(a22[si][sj][r] * ib4[r] * iBc[sj] * INV_TAU);
        rs11[r] += e11; rm11[r] += e11 * mv;
        rs12[r] += e12; rm12[r] += e12 * mv;
        cs12[sj] += e12; cm12[sj] += e12 * mv;
        cs22[sj] += e22; cm22[sj] += e22 * mv;
      }
    }
#pragma unroll
    for (int r = 0; r < 4; ++r) {
      float v0 = rs11[r], v1 = rm11[r], v2 = rs12[r], v3 = rm12[r];
#pragma unroll
      for (int o = 1; o < 16; o <<= 1) {
        v0 += __shfl_xor(v0, o, 64);
        v1 += __shfl_xor(v1, o, 64);
        v2 += __shfl_xor(v2, o, 64);
        v3 += __shfl_xor(v3, o, 64);
      }
      if (m16 == 0) {
        const int il = wi * 64 + si * 16 + quad * 4 + r;
        atomicAdd(&rred[0 * 128 + il], v0);
        atomicAdd(&rred[1 * 128 + il], v1);
        atomicAdd(&rred[2 * 128 + il], v2);
        atomicAdd(&rred[3 * 128 + il], v3);
      }
    }
  }
#pragma unroll
  for (int sj = 0; sj < 4; ++sj) {
    float v0 = cs12[sj], v1 = cm12[sj], v2 = cs22[sj], v3 = cm22[sj];
    v0 += __shfl_xor(v0, 16, 64); v0 += __shfl_xor(v0, 32, 64);
    v1 += __shfl_xor(v1, 16, 64); v1 += __shfl_xor(v1, 32, 64);
    v2 += __shfl_xor(v2, 16, 64); v2 += __shfl_xor(v2, 32, 64);
    v3 += __shfl_xor(v3, 16, 64); v3 += __shfl_xor(v3, 32, 64);
    if (lane < 16) {
      const int jl = wj * 64 + sj * 16 + lane;
      atomicAdd(&cred[0 * 128 + jl], v0);
      atomicAdd(&cred[1 * 128 + jl], v1);
      atomicAdd(&cred[2 * 128 + jl], v2);
      atomicAdd(&cred[3 * 128 + jl], v3);
    }
  }
  __syncthreads();
  if (tid < 128) {
#pragma unroll
    for (int q = 0; q < 4; ++q)
      atomicAdd(&zb[q * NN + i0 + tid], rred[q * 128 + tid]);
  } else {
    const int jl = tid - 128;
#pragma unroll
    for (int q = 0; q < 4; ++q)
      atomicAdd(&zb[(4 + q) * NN + j0 + jl], cred[q * 128 + jl]);
  }
}

// ---------------- paired D x D matvec, one wave per output row ---------------
__global__ __launch_bounds__(256) void matvec2(
    const float* __restrict__ M, const float* __restrict__ x1,
    const float* __restrict__ x2, const float* __restrict__ bias,
    const float* __restrict__ alpha_p, int act, float* __restrict__ y1,
    float* __restrict__ y2) {
  const float* x = blockIdx.y ? x2 : x1;
  float* y = blockIdx.y ? y2 : y1;
  const int row = (blockIdx.x * 256 + threadIdx.x) >> 6;
  const int lane = threadIdx.x & 63;
  float acc = 0.f;
#pragma unroll
  for (int t = 0; t < 8; ++t)
    acc = fmaf(M[(size_t)row * DD + lane + 64 * t], x[lane + 64 * t], acc);
  acc = wave_sum(acc);
  if (lane == 0) {
    if (bias) acc += bias[row];
    if (act) { const float al = alpha_p[0]; acc = (acc >= 0.f) ? acc : al * acc; }
    y[row] = acc;
  }
}

// ------- finalize: logsig (512 blocks) + local_fin (16 blocks) + combine -----
__global__ __launch_bounds__(256) void finalize(
    const float* __restrict__ zb, const u16* __restrict__ zb16,
    const float* __restrict__ sm1, const float* __restrict__ sm2,
    float* __restrict__ scal, float* __restrict__ out) {
  const int b = blockIdx.x;
  const int tid = threadIdx.x;
  if (b < 512) {
    // ---- logsig part ----
    const int ch = b >> 8, sub = b & 255;
    const u16* z = zb16 + (size_t)ch * ((size_t)NN * DD);
    const float* sp = ch ? sm2 : sm1;
    const float* sn = ch ? sm1 : sm2;
    const int lane = tid & 63, wv = tid >> 6;
    float sp8[8], sn8[8];
#pragma unroll
    for (int k = 0; k < 8; ++k) {
      sp8[k] = sp[lane * 8 + k];
      sn8[k] = sn[lane * 8 + k];
    }
    float accP = 0.f, accN = 0.f;
#pragma unroll
    for (int rr = 0; rr < 4; ++rr) {
      const int row = sub * 16 + wv * 4 + rr;
      short8 v = *(const short8*)&z[(size_t)row * DD + lane * 8];
      float dp = 0.f, dn = 0.f;
#pragma unroll
      for (int k = 0; k < 8; ++k) {
        const float f = bf2f(((const u16*)&v)[k]);
        dp = fmaf(f, sp8[k], dp);
        dn = fmaf(f, sn8[k], dn);
      }
      dp = wave_sum(dp);
      dn = wave_sum(dn);
      if (lane == 0) {
        accP += -logf(1.f / (1.f + __expf(-dp)) + EPSV);
        accN += -logf(1.f - 1.f / (1.f + __expf(-dn)) + EPSV);
      }
    }
    if (lane == 0) {
      atomicAdd(&scal[ch ? 4 : 2], accP);
      atomicAdd(&scal[ch ? 3 : 5], accN);
    }
  } else {
    // ---- local_fin part ----
    const int i = (b - 512) * 256 + tid;
    const float r11 = zb[i], r11m = zb[NN + i];
    const float r12 = zb[2 * NN + i], r12m = zb[3 * NN + i];
    const float c12 = zb[4 * NN + i], c12m = zb[5 * NN + i];
    const float c22 = zb[6 * NN + i], c22m = zb[7 * NN + i];
    float l1 = -logf(r12m / (r11 + r12 - r11m));
    float l2 = -logf(c12m / (c22 + c12 - c22m));
    l1 = wave_sum(l1);
    l2 = wave_sum(l2);
    __shared__ float b1[4], b2[4];
    const int lane = tid & 63, wid = tid >> 6;
    if (lane == 0) { b1[wid] = l1; b2[wid] = l2; }
    __syncthreads();
    if (tid == 0) {
      atomicAdd(&scal[0], b1[0] + b1[1] + b1[2] + b1[3]);
      atomicAdd(&scal[1], b2[0] + b2[1] + b2[2] + b2[3]);
    }
  }
  // ---- last block combines (device-scope counter; scal zeroed per call) ----
  __syncthreads();  // drains this block's memory ops (vmcnt(0) before barrier)
  if (tid == 0) {
    unsigned int* cnt = (unsigned int*)&scal[8];
    const unsigned old = atomicAdd(cnt, 1u);
    if (old == (unsigned)(gridDim.x - 1)) {
      // all other blocks' atomics complete; read via atomic RMW (coherent)
      const float s0 = atomicAdd(&scal[0], 0.f);
      const float s1 = atomicAdd(&scal[1], 0.f);
      const float p1 = atomicAdd(&scal[2], 0.f);
      const float n1 = atomicAdd(&scal[3], 0.f);
      const float p2 = atomicAdd(&scal[4], 0.f);
      const float n2 = atomicAdd(&scal[5], 0.f);
      const float local = 0.5f * (s0 + s1) * (1.f / NN);
      const float glob = 0.25f * (p1 + n1 + p2 + n2) * (1.f / NN);
      out[0] = 0.5f * local + 0.5f * glob;
    }
  }
}

extern "C" void kernel_launch(void* const* d_in, const int* in_sizes, int n_in,
                              void* d_out, int out_size, void* d_ws,
                              size_t ws_size, hipStream_t stream) {
  const float* z1 = (const float*)d_in[0];
  const float* z2 = (const float*)d_in[1];
  const float* lw1 = (const float*)d_in[2];
  const float* lb1 = (const float*)d_in[3];
  const float* la = (const float*)d_in[4];
  const float* lw2 = (const float*)d_in[5];
  const float* lb2 = (const float*)d_in[6];
  const float* gw1 = (const float*)d_in[7];
  const float* gb1 = (const float*)d_in[8];
  const float* ga = (const float*)d_in[9];
  const float* gw2 = (const float*)d_in[10];
  const float* gb2 = (const float*)d_in[11];
  const float* W = (const float*)d_in[12];
  const int* mask = (const int*)d_in[13];
  float* out = (float*)d_out;

  const size_t ND = (size_t)NN * DD;
  u16* W1b = (u16*)d_ws;                  // [2][512*512] bf16 contiguous
  u16* W2b = W1b + 512 * 512;
  u16* Ab = W1b + 2 * 512 * 512;          // [2][N*D] bf16 (z)
  u16* Pb = Ab + 2 * ND;                  // [2][N*D] bf16 (prelu out)
  u16* Hb = Pb + 2 * ND;                  // [2][N*D] bf16 (projector out)
  // ---- zeroed region start ----
  float* zbf = (float*)(Hb + 2 * ND);     // 8*NN
  float* norm2 = zbf + 8 * NN;            // [2*NN]
  float* s1 = norm2 + 2 * NN;             // DD
  float* s2 = s1 + DD;                    // DD
  float* scal = s2 + DD;                  // [16]: losses + counter at [8]
  // ---- zeroed region end ----
  float* summ1 = scal + 16;
  float* summ2 = summ1 + DD;
  float* t1 = summ2 + DD;
  float* t2 = t1 + DD;
  float* hg1 = t2 + DD;
  float* hg2 = hg1 + DD;

  hipMemsetAsync(zbf, 0, (10 * NN + 2 * DD + 16) * sizeof(float), stream);

  dim3 blk(256);
  prep<<<dim3(64, 3), blk, 0, stream>>>(z1, z2, lw1, lw2, Ab, W1b, s1, s2);

  dim3 gg(8, 32, 2);  // 512/64, 4096/128, batch
  gemm_mfma<1, 0><<<gg, blk, 0, stream>>>(Ab, W1b, lb1, la, Pb, nullptr);
  gemm_mfma<0, 1><<<gg, blk, 0, stream>>>(Pb, W2b, lb2, la, Hb, norm2);

  sim_mfma<<<dim3(NN / 128, NN / 128), blk, 0, stream>>>(
      Hb, Hb + ND, norm2, norm2 + NN, mask, zbf);

  // global (DGI) projector chain — 256-block matvecs (proven fast in r3)
  matvec2<<<dim3(DD / 4, 2), blk, 0, stream>>>(gw1, s1, s2, gb1, ga, 1, t1, t2);
  matvec2<<<dim3(DD / 4, 2), blk, 0, stream>>>(gw2, t1, t2, gb2, nullptr, 0, hg1, hg2);
  matvec2<<<dim3(DD / 4, 2), blk, 0, stream>>>(W, hg1, hg2, nullptr, nullptr, 0, summ1, summ2);

  finalize<<<528, blk, 0, stream>>>(zbf, Ab, summ1, summ2, scal, out);
}

// Round 6
// 334.678 us; speedup vs baseline: 1.3297x; 1.0142x over previous
//
#include <hip/hip_runtime.h>
#include <math.h>

#define NN 4096
#define DD 512
#define INV_TAU 5.0f
#define EPSV 1e-15f

typedef unsigned short u16;
typedef __attribute__((ext_vector_type(8))) short short8;
typedef __attribute__((ext_vector_type(4))) float f32x4;

__device__ __forceinline__ void gld16(const void* g, void* l) {
  __builtin_amdgcn_global_load_lds(
      (const __attribute__((address_space(1))) unsigned int*)g,
      (__attribute__((address_space(3))) unsigned int*)l, 16, 0, 0);
}

__device__ __forceinline__ float bf2f(u16 u) {
  return __uint_as_float(((unsigned)u) << 16);
}
__device__ __forceinline__ u16 f2bf(float x) {  // RNE
  unsigned u = __float_as_uint(x);
  u += 0x7fff + ((u >> 16) & 1);
  return (u16)(u >> 16);
}

__device__ __forceinline__ float wave_sum(float v) {
#pragma unroll
  for (int o = 32; o > 0; o >>= 1) v += __shfl_down(v, o, 64);
  return v;
}

__device__ __forceinline__ float invnorm(float n) {
  return 1.f / fmaxf(sqrtf(n), 1e-12f);
}

// ---- prep: z1/z2 fp32 -> bf16 + column means; weights fp32 -> bf16 ----------
__global__ __launch_bounds__(256) void prep(
    const float* __restrict__ z1, const float* __restrict__ z2,
    const float* __restrict__ lw1, const float* __restrict__ lw2,
    u16* __restrict__ Ab, u16* __restrict__ Wb, float* __restrict__ s1,
    float* __restrict__ s2) {
  const int tid = threadIdx.x;
  if (blockIdx.y == 2) {
#pragma unroll
    for (int k = 0; k < 8; ++k) {
      const int idx = blockIdx.x * 256 + tid + k * 16384;
      const float* s = (idx < 65536) ? &lw1[(size_t)idx * 4]
                                     : &lw2[(size_t)(idx - 65536) * 4];
      float4 v = *(const float4*)s;
      unsigned long long pk = (unsigned long long)f2bf(v.x) |
                              ((unsigned long long)f2bf(v.y) << 16) |
                              ((unsigned long long)f2bf(v.z) << 32) |
                              ((unsigned long long)f2bf(v.w) << 48);
      *(unsigned long long*)&Wb[(size_t)idx * 4] = pk;
    }
    return;
  }
  const float* z = blockIdx.y ? z2 : z1;
  u16* dst = Ab + (size_t)blockIdx.y * ((size_t)NN * DD);
  float* sdst = blockIdx.y ? s2 : s1;
  const int col4 = tid & 127;
  const int rg = tid >> 7;
  const int r0 = blockIdx.x * 64;
  float4 acc = make_float4(0.f, 0.f, 0.f, 0.f);
#pragma unroll 4
  for (int k = 0; k < 32; ++k) {
    const int r = r0 + rg + k * 2;
    float4 v = *(const float4*)&z[(size_t)r * DD + col4 * 4];
    acc.x += v.x; acc.y += v.y; acc.z += v.z; acc.w += v.w;
    unsigned long long pk = (unsigned long long)f2bf(v.x) |
                            ((unsigned long long)f2bf(v.y) << 16) |
                            ((unsigned long long)f2bf(v.z) << 32) |
                            ((unsigned long long)f2bf(v.w) << 48);
    *(unsigned long long*)&dst[(size_t)r * DD + col4 * 4] = pk;
  }
  const float inv = 1.f / NN;
  atomicAdd(&sdst[col4 * 4 + 0], acc.x * inv);
  atomicAdd(&sdst[col4 * 4 + 1], acc.y * inv);
  atomicAdd(&sdst[col4 * 4 + 2], acc.z * inv);
  atomicAdd(&sdst[col4 * 4 + 3], acc.w * inv);
}

// ------------- MFMA NT GEMM, pipelined: out = act(A@Bw^T + bias) -------------
template <int ACT, int NRM>
__global__ __launch_bounds__(256) void gemm_mfma(
    const u16* __restrict__ A, const u16* __restrict__ Bw,
    const float* __restrict__ bias, const float* __restrict__ alpha_p,
    u16* __restrict__ out, float* __restrict__ norm2) {
  __shared__ __align__(16) u16 sA[2][128 * 32], sB[2][64 * 32];
  const int tid = threadIdx.x, w = tid >> 6, lane = tid & 63;
  const int rq = lane >> 2, cq = (lane & 3) * 8;
  const int quad = lane >> 4, m16 = lane & 15;
  const int wi = w >> 1, wj = w & 1;
  const int i0 = blockIdx.y * 128, j0 = blockIdx.x * 64;
  const u16* Apan = A + (size_t)blockIdx.z * ((size_t)NN * DD);
  u16* ob = out + (size_t)blockIdx.z * ((size_t)NN * DD);
  float* npan = norm2 + (size_t)blockIdx.z * NN;
  const bool st = (w < 3);
  const u16* gs = (w == 2) ? Bw : Apan;
  const int gr0 = (w == 2) ? (j0 + rq) : (i0 + (w == 1 ? 64 : 0) + rq);
  u16* lb0 = (w == 2) ? sB[0] : &sA[0][(w == 1 ? 64 : 0) * 32];
  u16* lb1 = (w == 2) ? sB[1] : &sA[1][(w == 1 ? 64 : 0) * 32];
  if (st) {
#pragma unroll
    for (int rr = 0; rr < 64; rr += 16)
      gld16(&gs[(size_t)(gr0 + rr) * DD + cq], lb0 + rr * 32);
  }
  f32x4 acc[4][2] = {};
  for (int kc = 0; kc < 16; ++kc) {
    __syncthreads();
    if (kc < 15 && st) {
      const int kn = (kc + 1) * 32;
      u16* d = (kc & 1) ? lb0 : lb1;
#pragma unroll
      for (int rr = 0; rr < 64; rr += 16)
        gld16(&gs[(size_t)(gr0 + rr) * DD + kn + cq], d + rr * 32);
    }
    const u16* As = sA[kc & 1];
    const u16* Bs = sB[kc & 1];
    short8 bj[2];
#pragma unroll
    for (int sj = 0; sj < 2; ++sj)
      bj[sj] = *(const short8*)&Bs[(wj * 32 + sj * 16 + m16) * 32 + quad * 8];
#pragma unroll
    for (int si = 0; si < 4; ++si) {
      short8 ai = *(const short8*)&As[(wi * 64 + si * 16 + m16) * 32 + quad * 8];
#pragma unroll
      for (int sj = 0; sj < 2; ++sj)
        acc[si][sj] = __builtin_amdgcn_mfma_f32_16x16x32_bf16(
            ai, bj[sj], acc[si][sj], 0, 0, 0);
    }
  }
  const float al = ACT ? alpha_p[0] : 0.f;
  float ssq[4][4] = {};
#pragma unroll
  for (int si = 0; si < 4; ++si)
#pragma unroll
    for (int sj = 0; sj < 2; ++sj) {
      const int col = j0 + wj * 32 + sj * 16 + m16;
      const float bv = bias[col];
#pragma unroll
      for (int r = 0; r < 4; ++r) {
        const int row = i0 + wi * 64 + si * 16 + quad * 4 + r;
        float x = acc[si][sj][r] + bv;
        if (ACT) x = (x >= 0.f) ? x : al * x;
        const u16 xb = f2bf(x);
        ob[(size_t)row * DD + col] = xb;
        if (NRM) {
          const float xf = bf2f(xb);
          ssq[si][r] += xf * xf;
        }
      }
    }
  if (NRM) {
#pragma unroll
    for (int si = 0; si < 4; ++si)
#pragma unroll
      for (int r = 0; r < 4; ++r) {
        float s = ssq[si][r];
        s += __shfl_xor(s, 1, 64);
        s += __shfl_xor(s, 2, 64);
        s += __shfl_xor(s, 4, 64);
        s += __shfl_xor(s, 8, 64);
        if (m16 == 0)
          atomicAdd(&npan[i0 + wi * 64 + si * 16 + quad * 4 + r], s);
      }
  }
}

// ---- triangular fused similarity: blocks (bi<=bj), 64x64 tiles --------------
// Computes tile (I,J) of S11,S12,S22 + mirror tile (J,I) of S12 (e12lo).
// S11/S22 symmetric => mirror stats derived from the same tile.
// zb: [r11s, r11m, r12s, r12m, c12s, c12m, c22s, c22m] x NN.
__global__ __launch_bounds__(256, 3) void sim_tri(
    const u16* __restrict__ na, const u16* __restrict__ nb,
    const float* __restrict__ n2A, const float* __restrict__ n2B,
    const int* __restrict__ mask, float* __restrict__ zb) {
  __shared__ __align__(16) u16 sP[2][4][64 * 32];  // 32 KiB
  const int tid = threadIdx.x, w = tid >> 6, lane = tid & 63;
  const int rq = lane >> 2, cq = (lane & 3) * 8;
  const int quad = lane >> 4, m16 = lane & 15;
  const int wi = w >> 1, wj = w & 1;
  // ---- triangle decode: b -> (bi, bj), bi <= bj, 64 tiles/dim ----
  const int b = blockIdx.x;
  int bi = (int)((129.0f - sqrtf(16641.0f - 8.0f * (float)b)) * 0.5f);
  if (bi > 63) bi = 63;
  while (64 * bi - (bi * (bi - 1)) / 2 > b) --bi;
  while (64 * (bi + 1) - ((bi + 1) * bi) / 2 <= b) ++bi;
  const int bj = bi + (b - (64 * bi - (bi * (bi - 1)) / 2));
  const int i0 = bi * 64, j0 = bj * 64;
  const bool offd = (bi != bj);
  // staging: wave w stages panel w: 0 na@I, 1 nb@I, 2 na@J, 3 nb@J
  const u16* gs = (w & 1) ? nb : na;
  const int gr0 = ((w < 2) ? i0 : j0) + rq;
  u16* lb0 = &sP[0][w][0];
  u16* lb1 = &sP[1][w][0];
#pragma unroll
  for (int rr = 0; rr < 64; rr += 16)
    gld16(&gs[(size_t)(gr0 + rr) * DD + cq], lb0 + rr * 32);
  f32x4 a11[2][2] = {}, a12[2][2] = {}, a22[2][2] = {}, alo[2][2] = {};
  for (int kc = 0; kc < 16; ++kc) {
    __syncthreads();
    if (kc < 15) {
      const int kn = (kc + 1) * 32;
      u16* d = (kc & 1) ? lb0 : lb1;
#pragma unroll
      for (int rr = 0; rr < 64; rr += 16)
        gld16(&gs[(size_t)(gr0 + rr) * DD + kn + cq], d + rr * 32);
    }
    const u16* Ai = sP[kc & 1][0];
    const u16* Bi = sP[kc & 1][1];
    const u16* Aj = sP[kc & 1][2];
    const u16* Bj = sP[kc & 1][3];
    short8 ai[2], bi2[2], aj[2], bj2[2];
#pragma unroll
    for (int s = 0; s < 2; ++s) {
      ai[s] = *(const short8*)&Ai[(wi * 32 + s * 16 + m16) * 32 + quad * 8];
      bi2[s] = *(const short8*)&Bi[(wi * 32 + s * 16 + m16) * 32 + quad * 8];
      aj[s] = *(const short8*)&Aj[(wj * 32 + s * 16 + m16) * 32 + quad * 8];
      bj2[s] = *(const short8*)&Bj[(wj * 32 + s * 16 + m16) * 32 + quad * 8];
    }
#pragma unroll
    for (int si = 0; si < 2; ++si)
#pragma unroll
      for (int sj = 0; sj < 2; ++sj) {
        a11[si][sj] = __builtin_amdgcn_mfma_f32_16x16x32_bf16(ai[si], aj[sj], a11[si][sj], 0, 0, 0);
        a12[si][sj] = __builtin_amdgcn_mfma_f32_16x16x32_bf16(ai[si], bj2[sj], a12[si][sj], 0, 0, 0);
        a22[si][sj] = __builtin_amdgcn_mfma_f32_16x16x32_bf16(bi2[si], bj2[sj], a22[si][sj], 0, 0, 0);
      }
    if (offd) {
#pragma unroll
      for (int sj = 0; sj < 2; ++sj)
#pragma unroll
        for (int si = 0; si < 2; ++si)
          alo[sj][si] = __builtin_amdgcn_mfma_f32_16x16x32_bf16(aj[sj], bi2[si], alo[sj][si], 0, 0, 0);
    }
  }
  __syncthreads();
  // overlay buf0 (16 KB): mask(J,I) tile as bytes [64][68] + 4x4x64 reductions
  unsigned char* smT = (unsigned char*)&sP[0][0][0];
  float* red = (float*)(smT + 4608);  // 1024 floats
  float* rredI = red;                 // [4][64] -> zb[0..3]+i0
  float* credJ = red + 256;           // [4][64] -> zb[4..7]+j0
  float* rredJ = red + 512;           // [4][64] -> zb[0..3]+j0 (offd)
  float* credI = red + 768;           // [4][64] -> zb[4..7]+i0 (offd)
  if (offd) {
#pragma unroll
    for (int it = 0; it < 4; ++it) {
      const int linear = tid + it * 256;  // int4 idx, 64x16 per tile
      const int r = linear >> 4, c4 = (linear & 15) * 4;
      const int4 v = *(const int4*)&mask[(size_t)(j0 + r) * NN + i0 + c4];
      smT[r * 68 + c4 + 0] = (unsigned char)v.x;
      smT[r * 68 + c4 + 1] = (unsigned char)v.y;
      smT[r * 68 + c4 + 2] = (unsigned char)v.z;
      smT[r * 68 + c4 + 3] = (unsigned char)v.w;
    }
  }
  red[tid] = 0.f; red[tid + 256] = 0.f; red[tid + 512] = 0.f; red[tid + 768] = 0.f;
  __syncthreads();
  // norm factors
  float iAr[2][4], iBr[2][4], jAr[2][4], iAc[2], iBc[2], iBcI[2];
#pragma unroll
  for (int s = 0; s < 2; ++s) {
    const int ri = i0 + wi * 32 + s * 16 + quad * 4;
    const int rj = j0 + wj * 32 + s * 16 + quad * 4;
    float4 a4 = *(const float4*)&n2A[ri];
    float4 b4 = *(const float4*)&n2B[ri];
    float4 c4 = *(const float4*)&n2A[rj];
    iAr[s][0] = invnorm(a4.x); iAr[s][1] = invnorm(a4.y);
    iAr[s][2] = invnorm(a4.z); iAr[s][3] = invnorm(a4.w);
    iBr[s][0] = invnorm(b4.x); iBr[s][1] = invnorm(b4.y);
    iBr[s][2] = invnorm(b4.z); iBr[s][3] = invnorm(b4.w);
    jAr[s][0] = invnorm(c4.x); jAr[s][1] = invnorm(c4.y);
    jAr[s][2] = invnorm(c4.z); jAr[s][3] = invnorm(c4.w);
    iAc[s] = invnorm(n2A[j0 + wj * 32 + s * 16 + m16]);
    iBc[s] = invnorm(n2B[j0 + wj * 32 + s * 16 + m16]);
    iBcI[s] = invnorm(n2B[i0 + wi * 32 + s * 16 + m16]);
  }
  float cs12[2] = {}, cm12[2] = {}, cs22[2] = {}, cm22[2] = {};
  float ms11[2] = {}, mm11[2] = {};
  float cs12I[2] = {}, cm12I[2] = {};
#pragma unroll
  for (int si = 0; si < 2; ++si) {
    float rs11[4] = {}, rm11[4] = {}, rs12[4] = {}, rm12[4] = {};
    float xs22[4] = {}, xm22[4] = {};
    const int il0 = wi * 32 + si * 16 + quad * 4;
#pragma unroll
    for (int sj = 0; sj < 2; ++sj) {
      const int jl = wj * 32 + sj * 16 + m16;
      const int gj = j0 + jl;
#pragma unroll
      for (int r = 0; r < 4; ++r) {
        const int il = il0 + r;
        const float mv = (float)mask[(size_t)(i0 + il) * NN + gj];
        const float e11 = __expf(a11[si][sj][r] * iAr[si][r] * iAc[sj] * INV_TAU);
        const float e12 = __expf(a12[si][sj][r] * iAr[si][r] * iBc[sj] * INV_TAU);
        const float e22 = __expf(a22[si][sj][r] * iBr[si][r] * iBc[sj] * INV_TAU);
        rs11[r] += e11; rm11[r] += e11 * mv;
        rs12[r] += e12; rm12[r] += e12 * mv;
        cs12[sj] += e12; cm12[sj] += e12 * mv;
        cs22[sj] += e22; cm22[sj] += e22 * mv;
        if (offd) {
          const float mt = (float)smT[jl * 68 + il];
          ms11[sj] += e11; mm11[sj] += e11 * mt;
          xs22[r] += e22; xm22[r] += e22 * mt;
        }
      }
    }
#pragma unroll
    for (int r = 0; r < 4; ++r) {
      float v0 = rs11[r], v1 = rm11[r], v2 = rs12[r], v3 = rm12[r];
      float v4 = xs22[r], v5 = xm22[r];
#pragma unroll
      for (int o = 1; o < 16; o <<= 1) {
        v0 += __shfl_xor(v0, o, 64); v1 += __shfl_xor(v1, o, 64);
        v2 += __shfl_xor(v2, o, 64); v3 += __shfl_xor(v3, o, 64);
        v4 += __shfl_xor(v4, o, 64); v5 += __shfl_xor(v5, o, 64);
      }
      if (m16 == 0) {
        const int il = il0 + r;
        atomicAdd(&rredI[0 * 64 + il], v0);
        atomicAdd(&rredI[1 * 64 + il], v1);
        atomicAdd(&rredI[2 * 64 + il], v2);
        atomicAdd(&rredI[3 * 64 + il], v3);
        if (offd) {
          atomicAdd(&credI[2 * 64 + il], v4);
          atomicAdd(&credI[3 * 64 + il], v5);
        }
      }
    }
  }
  if (offd) {
#pragma unroll
    for (int sj = 0; sj < 2; ++sj) {
      float rsJ[4] = {}, rmJ[4] = {};
      const int jr0 = wj * 32 + sj * 16 + quad * 4;
#pragma unroll
      for (int si = 0; si < 2; ++si) {
        const int ic = wi * 32 + si * 16 + m16;
#pragma unroll
        for (int r = 0; r < 4; ++r) {
          const int jr = jr0 + r;
          const float e12l = __expf(alo[sj][si][r] * jAr[sj][r] * iBcI[si] * INV_TAU);
          const float mt2 = (float)smT[jr * 68 + ic];
          rsJ[r] += e12l; rmJ[r] += e12l * mt2;
          cs12I[si] += e12l; cm12I[si] += e12l * mt2;
        }
      }
#pragma unroll
      for (int r = 0; r < 4; ++r) {
        float v0 = rsJ[r], v1 = rmJ[r];
#pragma unroll
        for (int o = 1; o < 16; o <<= 1) {
          v0 += __shfl_xor(v0, o, 64);
          v1 += __shfl_xor(v1, o, 64);
        }
        if (m16 == 0) {
          atomicAdd(&rredJ[2 * 64 + jr0 + r], v0);
          atomicAdd(&rredJ[3 * 64 + jr0 + r], v1);
        }
      }
    }
  }
#pragma unroll
  for (int s = 0; s < 2; ++s) {
    float v0 = cs12[s], v1 = cm12[s], v2 = cs22[s], v3 = cm22[s];
    float v4 = ms11[s], v5 = mm11[s], v6 = cs12I[s], v7 = cm12I[s];
    v0 += __shfl_xor(v0, 16, 64); v0 += __shfl_xor(v0, 32, 64);
    v1 += __shfl_xor(v1, 16, 64); v1 += __shfl_xor(v1, 32, 64);
    v2 += __shfl_xor(v2, 16, 64); v2 += __shfl_xor(v2, 32, 64);
    v3 += __shfl_xor(v3, 16, 64); v3 += __shfl_xor(v3, 32, 64);
    v4 += __shfl_xor(v4, 16, 64); v4 += __shfl_xor(v4, 32, 64);
    v5 += __shfl_xor(v5, 16, 64); v5 += __shfl_xor(v5, 32, 64);
    v6 += __shfl_xor(v6, 16, 64); v6 += __shfl_xor(v6, 32, 64);
    v7 += __shfl_xor(v7, 16, 64); v7 += __shfl_xor(v7, 32, 64);
    if (lane < 16) {
      const int jl = wj * 32 + s * 16 + lane;
      const int ic = wi * 32 + s * 16 + lane;
      atomicAdd(&credJ[0 * 64 + jl], v0);
      atomicAdd(&credJ[1 * 64 + jl], v1);
      atomicAdd(&credJ[2 * 64 + jl], v2);
      atomicAdd(&credJ[3 * 64 + jl], v3);
      if (offd) {
        atomicAdd(&rredJ[0 * 64 + jl], v4);
        atomicAdd(&rredJ[1 * 64 + jl], v5);
        atomicAdd(&credI[0 * 64 + ic], v6);
        atomicAdd(&credI[1 * 64 + ic], v7);
      }
    }
  }
  __syncthreads();
  const int g = tid >> 6, t = tid & 63;
  if (g == 0) {
#pragma unroll
    for (int q = 0; q < 4; ++q) atomicAdd(&zb[q * NN + i0 + t], rredI[q * 64 + t]);
  } else if (g == 1) {
#pragma unroll
    for (int q = 0; q < 4; ++q) atomicAdd(&zb[(4 + q) * NN + j0 + t], credJ[q * 64 + t]);
  } else if (g == 2 && offd) {
#pragma unroll
    for (int q = 0; q < 4; ++q) atomicAdd(&zb[q * NN + j0 + t], rredJ[q * 64 + t]);
  } else if (g == 3 && offd) {
#pragma unroll
    for (int q = 0; q < 4; ++q) atomicAdd(&zb[(4 + q) * NN + i0 + t], credI[q * 64 + t]);
  }
}

// ---------------- paired D x D matvec, one wave per output row ---------------
__global__ __launch_bounds__(256) void matvec2(
    const float* __restrict__ M, const float* __restrict__ x1,
    const float* __restrict__ x2, const float* __restrict__ bias,
    const float* __restrict__ alpha_p, int act, float* __restrict__ y1,
    float* __restrict__ y2) {
  const float* x = blockIdx.y ? x2 : x1;
  float* y = blockIdx.y ? y2 : y1;
  const int row = (blockIdx.x * 256 + threadIdx.x) >> 6;
  const int lane = threadIdx.x & 63;
  float acc = 0.f;
#pragma unroll
  for (int t = 0; t < 8; ++t)
    acc = fmaf(M[(size_t)row * DD + lane + 64 * t], x[lane + 64 * t], acc);
  acc = wave_sum(acc);
  if (lane == 0) {
    if (bias) acc += bias[row];
    if (act) { const float al = alpha_p[0]; acc = (acc >= 0.f) ? acc : al * acc; }
    y[row] = acc;
  }
}

// ------- finalize: logsig (512 blocks) + local_fin (16 blocks) + combine -----
__global__ __launch_bounds__(256) void finalize(
    const float* __restrict__ zb, const u16* __restrict__ zb16,
    const float* __restrict__ sm1, const float* __restrict__ sm2,
    float* __restrict__ scal, float* __restrict__ out) {
  const int b = blockIdx.x;
  const int tid = threadIdx.x;
  if (b < 512) {
    const int ch = b >> 8, sub = b & 255;
    const u16* z = zb16 + (size_t)ch * ((size_t)NN * DD);
    const float* sp = ch ? sm2 : sm1;
    const float* sn = ch ? sm1 : sm2;
    const int lane = tid & 63, wv = tid >> 6;
    float sp8[8], sn8[8];
#pragma unroll
    for (int k = 0; k < 8; ++k) {
      sp8[k] = sp[lane * 8 + k];
      sn8[k] = sn[lane * 8 + k];
    }
    float accP = 0.f, accN = 0.f;
#pragma unroll
    for (int rr = 0; rr < 4; ++rr) {
      const int row = sub * 16 + wv * 4 + rr;
      short8 v = *(const short8*)&z[(size_t)row * DD + lane * 8];
      float dp = 0.f, dn = 0.f;
#pragma unroll
      for (int k = 0; k < 8; ++k) {
        const float f = bf2f(((const u16*)&v)[k]);
        dp = fmaf(f, sp8[k], dp);
        dn = fmaf(f, sn8[k], dn);
      }
      dp = wave_sum(dp);
      dn = wave_sum(dn);
      if (lane == 0) {
        accP += -logf(1.f / (1.f + __expf(-dp)) + EPSV);
        accN += -logf(1.f - 1.f / (1.f + __expf(-dn)) + EPSV);
      }
    }
    if (lane == 0) {
      atomicAdd(&scal[ch ? 4 : 2], accP);
      atomicAdd(&scal[ch ? 3 : 5], accN);
    }
  } else {
    const int i = (b - 512) * 256 + tid;
    const float r11 = zb[i], r11m = zb[NN + i];
    const float r12 = zb[2 * NN + i], r12m = zb[3 * NN + i];
    const float c12 = zb[4 * NN + i], c12m = zb[5 * NN + i];
    const float c22 = zb[6 * NN + i], c22m = zb[7 * NN + i];
    float l1 = -logf(r12m / (r11 + r12 - r11m));
    float l2 = -logf(c12m / (c22 + c12 - c22m));
    l1 = wave_sum(l1);
    l2 = wave_sum(l2);
    __shared__ float b1[4], b2[4];
    const int lane = tid & 63, wid = tid >> 6;
    if (lane == 0) { b1[wid] = l1; b2[wid] = l2; }
    __syncthreads();
    if (tid == 0) {
      atomicAdd(&scal[0], b1[0] + b1[1] + b1[2] + b1[3]);
      atomicAdd(&scal[1], b2[0] + b2[1] + b2[2] + b2[3]);
    }
  }
  __syncthreads();
  if (tid == 0) {
    unsigned int* cnt = (unsigned int*)&scal[8];
    const unsigned old = atomicAdd(cnt, 1u);
    if (old == (unsigned)(gridDim.x - 1)) {
      const float s0 = atomicAdd(&scal[0], 0.f);
      const float s1 = atomicAdd(&scal[1], 0.f);
      const float p1 = atomicAdd(&scal[2], 0.f);
      const float n1 = atomicAdd(&scal[3], 0.f);
      const float p2 = atomicAdd(&scal[4], 0.f);
      const float n2 = atomicAdd(&scal[5], 0.f);
      const float local = 0.5f * (s0 + s1) * (1.f / NN);
      const float glob = 0.25f * (p1 + n1 + p2 + n2) * (1.f / NN);
      out[0] = 0.5f * local + 0.5f * glob;
    }
  }
}

extern "C" void kernel_launch(void* const* d_in, const int* in_sizes, int n_in,
                              void* d_out, int out_size, void* d_ws,
                              size_t ws_size, hipStream_t stream) {
  const float* z1 = (const float*)d_in[0];
  const float* z2 = (const float*)d_in[1];
  const float* lw1 = (const float*)d_in[2];
  const float* lb1 = (const float*)d_in[3];
  const float* la = (const float*)d_in[4];
  const float* lw2 = (const float*)d_in[5];
  const float* lb2 = (const float*)d_in[6];
  const float* gw1 = (const float*)d_in[7];
  const float* gb1 = (const float*)d_in[8];
  const float* ga = (const float*)d_in[9];
  const float* gw2 = (const float*)d_in[10];
  const float* gb2 = (const float*)d_in[11];
  const float* W = (const float*)d_in[12];
  const int* mask = (const int*)d_in[13];
  float* out = (float*)d_out;

  const size_t ND = (size_t)NN * DD;
  u16* W1b = (u16*)d_ws;
  u16* W2b = W1b + 512 * 512;
  u16* Ab = W1b + 2 * 512 * 512;
  u16* Pb = Ab + 2 * ND;
  u16* Hb = Pb + 2 * ND;
  // ---- zeroed region start ----
  float* zbf = (float*)(Hb + 2 * ND);     // 8*NN
  float* norm2 = zbf + 8 * NN;            // 2*NN
  float* s1 = norm2 + 2 * NN;
  float* s2 = s1 + DD;
  float* scal = s2 + DD;                  // [16], counter at [8]
  // ---- zeroed region end ----
  float* summ1 = scal + 16;
  float* summ2 = summ1 + DD;
  float* t1 = summ2 + DD;
  float* t2 = t1 + DD;
  float* hg1 = t2 + DD;
  float* hg2 = hg1 + DD;

  hipMemsetAsync(zbf, 0, (10 * NN + 2 * DD + 16) * sizeof(float), stream);

  dim3 blk(256);
  prep<<<dim3(64, 3), blk, 0, stream>>>(z1, z2, lw1, lw2, Ab, W1b, s1, s2);

  dim3 gg(8, 32, 2);
  gemm_mfma<1, 0><<<gg, blk, 0, stream>>>(Ab, W1b, lb1, la, Pb, nullptr);
  gemm_mfma<0, 1><<<gg, blk, 0, stream>>>(Pb, W2b, lb2, la, Hb, norm2);

  sim_tri<<<2080, blk, 0, stream>>>(Hb, Hb + ND, norm2, norm2 + NN, mask, zbf);

  matvec2<<<dim3(DD / 4, 2), blk, 0, stream>>>(gw1, s1, s2, gb1, ga, 1, t1, t2);
  matvec2<<<dim3(DD / 4, 2), blk, 0, stream>>>(gw2, t1, t2, gb2, nullptr, 0, hg1, hg2);
  matvec2<<<dim3(DD / 4, 2), blk, 0, stream>>>(W, hg1, hg2, nullptr, nullptr, 0, summ1, summ2);

  finalize<<<528, blk, 0, stream>>>(zbf, Ab, summ1, summ2, scal, out);
}